// Round 9
// baseline (422.660 us; speedup 1.0000x reference)
//
#include <hip/hip_runtime.h>
#include <hip/hip_bf16.h>
#include <cstdint>
#include <cstddef>

// Problem shape (fixed by reference): B=8, N=1024, D=768, H=12, dh=64, 3 branches
#define B_   8
#define N_   1024
#define D_   768
#define H_   12
#define DH_  64
#define M_   (B_ * N_)          // 8192 rows
#define WSZ_ (D_ * D_)          // 589824 per weight matrix

typedef __bf16 bf16;
typedef bf16  bf16x8  __attribute__((ext_vector_type(8)));
typedef bf16  bf16x4  __attribute__((ext_vector_type(4)));
typedef float floatx4 __attribute__((ext_vector_type(4)));

#define MFMA16 __builtin_amdgcn_mfma_f32_16x16x32_bf16

// raw v_exp_f32: D = 2^S0
__device__ __forceinline__ float exp2_fast(float x) {
    float r;
    asm("v_exp_f32 %0, %1" : "=v"(r) : "v"(x));
    return r;
}

// ---------------------------------------------------------------------------
// async global->LDS, 16B per lane (wave-uniform LDS base + lane*16)
__device__ __forceinline__ void gload_lds16(const void* g, void* l) {
    __builtin_amdgcn_global_load_lds(
        (const __attribute__((address_space(1))) unsigned int*)g,
        (__attribute__((address_space(3))) unsigned int*)l, 16, 0, 0);
}

// ---------------------------------------------------------------------------
// Kernel 1: per-row norm -> branch scales; x -> bf16. 192 threads, float4.
__global__ __launch_bounds__(192) void prep_x(const float* __restrict__ x,
                                              bf16* __restrict__ xbf,
                                              float* __restrict__ sc /* [2][M_] */) {
    int row = blockIdx.x;
    int tid = threadIdx.x;
    const float* xr = x + (size_t)row * D_;
    float4 v = *(const float4*)(xr + tid * 4);
    bf16x4 o = { (bf16)v.x, (bf16)v.y, (bf16)v.z, (bf16)v.w };
    *(bf16x4*)(xbf + (size_t)row * D_ + tid * 4) = o;
    float ss = v.x * v.x + v.y * v.y + v.z * v.z + v.w * v.w;
    for (int off = 32; off; off >>= 1) ss += __shfl_xor(ss, off, 64);
    __shared__ float red[3];
    if ((tid & 63) == 0) red[tid >> 6] = ss;
    __syncthreads();
    if (tid == 0) {
        float t2 = red[0] + red[1] + red[2];
        float t  = sqrtf(t2);                       // true ||x||
        const float scst = 0.31622776601683794f;    // sqrt(0.1)
        float un = fmaxf(t, 1e-5f);
        float s1 = tanhf(scst * un) / (scst * un);
        float nh = fmaxf(t * s1, 1e-5f);
        float maxnorm = (1.0f - 4e-3f) / scst;
        float sh = (nh > maxnorm) ? s1 * (maxnorm / nh) : s1;
        float arg = fminf(scst * un, 1.0f - 1e-5f);
        float artanh = 0.5f * logf((1.0f + arg) / (1.0f - arg));
        float ssc = artanh / (un * scst);
        sc[row]      = sh;
        sc[M_ + row] = ssc;
    }
}

// ---------------------------------------------------------------------------
// Kernel 2: weights fp32 -> bf16, layout wbf[branch][t][o][k] == stacked [6912][768]
__global__ __launch_bounds__(256) void prep_w(const float* __restrict__ wq,
                                              const float* __restrict__ wk,
                                              const float* __restrict__ wv,
                                              bf16* __restrict__ wbf) {
    size_t i = ((size_t)blockIdx.x * 256 + threadIdx.x) * 4;  // 9*WSZ_ total
    int z = (int)(i / WSZ_);
    int r = (int)(i % WSZ_);
    int branch = z / 3, t = z % 3;
    const float* src = (t == 0 ? wq : t == 1 ? wk : wv) + (size_t)branch * WSZ_ + r;
    float4 f = *(const float4*)src;
    bf16x4 o = { (bf16)f.x, (bf16)f.y, (bf16)f.z, (bf16)f.w };
    *(bf16x4*)(wbf + i) = o;
}

// ---------------------------------------------------------------------------
// Kernel 3 (merged path, verified r6/r7): 256x256-tile 8-phase pipelined GEMM
// over stacked N = 9*768. For t==2 (V) the output is written TRANSPOSED per
// (b,h): vt[b][h][dd][n] (bf16x4 packs along n).
#define NT9 12   // K tiles: 768/64

#define STG(buf, mat, half, t) do {                                          \
    const bf16* _src = (mat) ? wbf : xbf;                                    \
    int _rb = ((mat) ? bn0 : bm0) + (half) * 128 + w * 16 + (lane >> 2);     \
    const bf16* _g = _src + (size_t)_rb * D_ + (t) * 64 + (lane & 3) * 8;    \
    bf16* _l = &L[buf][mat][half][0][w * 16][0];                             \
    gload_lds16(_g, _l);                                                     \
    gload_lds16(_g + 32, _l + 4096);                                         \
} while (0)

#define LOADA(buf, mh) do {                                                  \
    _Pragma("unroll") for (int fi = 0; fi < 4; fi++)                         \
    _Pragma("unroll") for (int kk = 0; kk < 2; kk++)                         \
        afr[fi][kk] = *(const bf16x8*)(&L[buf][0][wm][kk][(mh)*64 + fi*16 + c15][quad*8]); \
} while (0)

#define LOADB(buf, nh) do {                                                  \
    _Pragma("unroll") for (int fj = 0; fj < 2; fj++)                         \
    _Pragma("unroll") for (int kk = 0; kk < 2; kk++)                         \
        bfr[nh][fj][kk] = *(const bf16x8*)(&L[buf][1][wn>>1][kk][(wn&1)*64 + (nh)*32 + fj*16 + c15][quad*8]); \
} while (0)

#define MFMACL(mh, nh) do {                                                  \
    __builtin_amdgcn_s_setprio(1);                                           \
    _Pragma("unroll") for (int fi = 0; fi < 4; fi++)                         \
    _Pragma("unroll") for (int fj = 0; fj < 2; fj++)                         \
    _Pragma("unroll") for (int kk = 0; kk < 2; kk++)                         \
        acc[(mh)*4 + fi][(nh)*2 + fj] =                                      \
            MFMA16(afr[fi][kk], bfr[nh][fj][kk], acc[(mh)*4 + fi][(nh)*2 + fj], 0, 0, 0); \
    __builtin_amdgcn_s_setprio(0);                                           \
} while (0)

#define BAR() __builtin_amdgcn_s_barrier()
#define VMW4() asm volatile("s_waitcnt vmcnt(4)" ::: "memory")

__global__ __launch_bounds__(512, 2) void gemm_qkv9(
        const bf16* __restrict__ xbf, const bf16* __restrict__ wbf,
        const float* __restrict__ bq, const float* __restrict__ bk,
        const float* __restrict__ bv, const float* __restrict__ sc,
        bf16* __restrict__ qkv) {
    int bid = blockIdx.x;
    int v = (bid & 7) * 108 + (bid >> 3);   // 864 = 8*108, bijective
    int bx = v >> 5;                        // N-panel (0..26)
    int by = v & 31;                        // M-panel (0..31)
    int bn0 = bx * 256;
    int bm0 = by * 256;

    __shared__ bf16 L[2][2][2][2][128][32]; // 128 KiB

    int tid = threadIdx.x;
    int w = tid >> 6, lane = tid & 63;
    int wm = w >> 2, wn = w & 3;
    int quad = lane >> 4, c15 = lane & 15;

    bf16x8 afr[4][2];
    bf16x8 bfr[2][2][2];
    floatx4 acc[8][4];
#pragma unroll
    for (int i = 0; i < 8; i++)
#pragma unroll
        for (int j = 0; j < 4; j++) acc[i][j] = (floatx4){0.f, 0.f, 0.f, 0.f};

    STG(0, 0, 0, 0); STG(0, 0, 1, 0); STG(0, 1, 0, 0); STG(0, 1, 1, 0);
    STG(1, 1, 0, 1); STG(1, 1, 1, 1);
    VMW4();
    BAR();

    for (int it = 0; it < 6; it++) {
        int t1 = 2 * it + 1;
        bool st2 = (it < 5);
        LOADA(0, 0); LOADB(0, 0);
        STG(1, 0, 0, t1);
        BAR(); MFMACL(0, 0); BAR();
        LOADB(0, 1);
        STG(1, 0, 1, t1);
        BAR(); MFMACL(0, 1); BAR();
        LOADA(0, 1);
        if (st2) STG(0, 1, 0, t1 + 1);
        BAR(); MFMACL(1, 1); BAR();
        if (st2) STG(0, 1, 1, t1 + 1);
        VMW4();
        BAR(); MFMACL(1, 0); BAR();
        LOADA(1, 0); LOADB(1, 0);
        if (st2) STG(0, 0, 0, t1 + 1);
        BAR(); MFMACL(0, 0); BAR();
        LOADB(1, 1);
        if (st2) STG(0, 0, 1, t1 + 1);
        BAR(); MFMACL(0, 1); BAR();
        LOADA(1, 1);
        if (st2) STG(1, 1, 0, t1 + 2);
        BAR(); MFMACL(1, 1); BAR();
        if (st2) STG(1, 1, 1, t1 + 2);
        VMW4();
        BAR(); MFMACL(1, 0); BAR();
    }

    // epilogue: y = s[row]*y + bias[col]
    int gz = bn0 / 768;
    int branch = gz / 3, t = gz % 3;
    int colz0 = (bn0 % 768) + wn * 64;
    const float* bias = (t == 0 ? bq : t == 1 ? bk : bv) + branch * D_;
    const float* scb = (branch == 0) ? nullptr : sc + (size_t)(branch - 1) * M_;
    float bj[4];
#pragma unroll
    for (int fj = 0; fj < 4; fj++) bj[fj] = bias[colz0 + fj * 16 + c15];
    bf16* outz = qkv + (size_t)gz * M_ * D_;
#pragma unroll
    for (int fi = 0; fi < 8; fi++) {
        int rowbase = bm0 + wm * 128 + fi * 16 + quad * 4;
        float4 sv = scb ? *(const float4*)(scb + rowbase)
                        : (float4){1.f, 1.f, 1.f, 1.f};
        float svr[4] = { sv.x, sv.y, sv.z, sv.w };
        if (t == 2) {
            // V: write transposed vt[b][h][dd][n], bf16x4 along n
            int b = rowbase >> 10, nn = rowbase & 1023;
#pragma unroll
            for (int fj = 0; fj < 4; fj++) {
                int col = colz0 + fj * 16 + c15;
                int h = col >> 6, dd = col & 63;
                bf16x4 pkv;
#pragma unroll
                for (int r = 0; r < 4; r++)
                    pkv[r] = (bf16)(svr[r] * acc[fi][fj][r] + bj[fj]);
                *(bf16x4*)(outz + (((size_t)(b * H_ + h) * 64 + dd) << 10) + nn) = pkv;
            }
        } else {
#pragma unroll
            for (int r = 0; r < 4; r++) {
                bf16* orow = outz + (size_t)(rowbase + r) * D_;
#pragma unroll
                for (int fj = 0; fj < 4; fj++)
                    orow[colz0 + fj * 16 + c15] = (bf16)(svr[r] * acc[fi][fj][r] + bj[fj]);
            }
        }
    }
}

// ---------------------------------------------------------------------------
// Kernel 3b (fallback path): 128x128 m97-style GEMM; t==2 writes V^T layout.
#define BM 128
#define BN 128
#define BK 32
__global__ __launch_bounds__(256) void gemm_qkv(
        const bf16* __restrict__ xbf, const bf16* __restrict__ wbf_all,
        const float* __restrict__ bq, const float* __restrict__ bk,
        const float* __restrict__ bv, const float* __restrict__ sc,
        int zoff, bf16* __restrict__ qkv) {
    int gz = zoff + blockIdx.z;
    int branch = gz / 3, t = gz % 3;
    const bf16*  wsrc = wbf_all + (size_t)gz * WSZ_;
    const float* bias = (t == 0 ? bq : t == 1 ? bk : bv) + branch * D_;
    bf16* out = qkv + (size_t)blockIdx.z * M_ * D_;
    int bm0 = blockIdx.y * BM;
    int bn0 = blockIdx.x * BN;

    __shared__ bf16 lA[BM * BK];
    __shared__ bf16 lB[BN * BK];

    int tid = threadIdx.x;
    int w = tid >> 6, lane = tid & 63;
    int wr = w >> 1, wc = w & 1;
    int quad = lane >> 4, c15 = lane & 15;
    int lrow = lane >> 2;
    int lcol = (lane & 3) * 8;

    floatx4 acc[4][4];
    for (int i = 0; i < 4; i++)
        for (int j = 0; j < 4; j++)
            acc[i][j] = (floatx4){0.f, 0.f, 0.f, 0.f};

    for (int k0 = 0; k0 < D_; k0 += BK) {
        const bf16* ga = xbf  + ((size_t)(bm0 + w * 32 + lrow) * D_ + k0 + lcol);
        const bf16* gb = wsrc + ((size_t)(bn0 + w * 32 + lrow) * D_ + k0 + lcol);
        gload_lds16(ga,           (char*)lA + w * 2048);
        gload_lds16(ga + 16 * D_, (char*)lA + w * 2048 + 1024);
        gload_lds16(gb,           (char*)lB + w * 2048);
        gload_lds16(gb + 16 * D_, (char*)lB + w * 2048 + 1024);
        __syncthreads();

        int arow = wr * 64 + c15;
        int brow = wc * 64 + c15;
        int kq = quad * 8;
        bf16x8 af[4], bfm[4];
        for (int i = 0; i < 4; i++) af[i]  = *(const bf16x8*)(lA + (arow + i * 16) * BK + kq);
        for (int j = 0; j < 4; j++) bfm[j] = *(const bf16x8*)(lB + (brow + j * 16) * BK + kq);
        for (int i = 0; i < 4; i++)
            for (int j = 0; j < 4; j++)
                acc[i][j] = MFMA16(af[i], bfm[j], acc[i][j], 0, 0, 0);
        __syncthreads();
    }

    const float* scb = (branch == 0) ? nullptr : sc + (size_t)(branch - 1) * M_;
    float bj[4];
    for (int j = 0; j < 4; j++) bj[j] = bias[bn0 + wc * 64 + j * 16 + c15];
    for (int i = 0; i < 4; i++) {
        int gRow0 = bm0 + wr * 64 + i * 16 + quad * 4;
        float s[4];
        for (int r = 0; r < 4; r++) s[r] = scb ? scb[gRow0 + r] : 1.0f;
        if (t == 2) {
            int b = gRow0 >> 10, nn = gRow0 & 1023;
            for (int j = 0; j < 4; j++) {
                int col = bn0 + wc * 64 + j * 16 + c15;
                int h = col >> 6, dd = col & 63;
                bf16x4 pkv;
                for (int r = 0; r < 4; r++)
                    pkv[r] = (bf16)(s[r] * acc[i][j][r] + bj[j]);
                *(bf16x4*)(out + (((size_t)(b * H_ + h) * 64 + dd) << 10) + nn) = pkv;
            }
        } else {
            for (int r = 0; r < 4; r++) {
                bf16* orow = out + (size_t)(gRow0 + r) * D_;
                for (int j = 0; j < 4; j++) {
                    int gCol = bn0 + wc * 64 + j * 16 + c15;
                    orow[gCol] = (bf16)(s[r] * acc[i][j][r] + bj[j]);
                }
            }
        }
    }
}

// ---------------------------------------------------------------------------
// Kernel 4: flash attention. Round-6 skeleton (dbuf async K/V^T staging with
// source-swizzle pair, swapped QK^T, exp2 softmax with defer-max) with LDS
// shrunk to exactly 40 KB -> 4 blocks/CU: sP is [4][16][64] (one half at a
// time, XOR-swizzled cols), V-frags hoisted to registers once per tile.
__global__ __launch_bounds__(256, 4) void attn(const bf16* __restrict__ qkv,
                                               float* __restrict__ out) {
    int qt = blockIdx.x;              // 0..7 (128 q rows each)
    int bh = blockIdx.y;              // 0..95
    int br = blockIdx.z;
    int batch = bh / H_, head = bh % H_;
    int n0 = qt * 128;
    int tid = threadIdx.x, w = tid >> 6, lane = tid & 63;
    int quad = lane >> 4, c15 = lane & 15;

    const bf16* base = qkv + (size_t)br * 3 * M_ * D_;
    size_t baseRow = (size_t)batch * N_;
    int colOff = head * DH_;
    const bf16* qb  = base;
    const bf16* kb  = base + (size_t)M_ * D_;
    const bf16* vtb = base + (size_t)2 * M_ * D_
                    + ((size_t)(batch * H_ + head) * 64) * 1024;

    __shared__ bf16 sK[2][64][64];       // 16 KB
    __shared__ bf16 sV[2][64][64];       // 16 KB
    __shared__ bf16 sP[4][16][64];       //  8 KB, wave-private (one half)

    int lr  = lane >> 3;
    int swz = ((lane & 7) ^ lr) * 8;     // staging: swizzled global col seg
    const bf16* kgl = kb  + (baseRow + w * 8 + lr) * D_ + colOff + swz;
    const bf16* vgl = vtb + ((size_t)(w * 8 + lr)) * 1024 + swz;

    int s0 = (quad ^ (c15 & 7)) * 8;     // K/V fragment read segs
    int s1 = s0 ^ 32;
    int spx = (c15 & 7) * 8;             // sP col XOR (row = c15)

    // Q fragments for both 16-row halves, pre-scaled by log2(e)
    bf16x8 aq[2][2];
#pragma unroll
    for (int h = 0; h < 2; h++) {
        const bf16* qp = qb + ((baseRow + n0 + w * 32 + h * 16 + c15) * D_ + colOff + quad * 8);
        aq[h][0] = *(const bf16x8*)qp;
        aq[h][1] = *(const bf16x8*)(qp + 32);
#pragma unroll
        for (int f = 0; f < 2; f++)
#pragma unroll
            for (int i = 0; i < 8; i++)
                aq[h][f][i] = (bf16)((float)aq[h][f][i] * 1.4426950408889634f);
    }

    float m_sw[2] = { 0.f, 0.f };
    float l_sw[2] = { 0.f, 0.f };
    floatx4 o_acc[2][4];
#pragma unroll
    for (int h = 0; h < 2; h++)
#pragma unroll
        for (int j = 0; j < 4; j++) o_acc[h][j] = (floatx4){0.f, 0.f, 0.f, 0.f};

    // prologue: stage tile 0 into buf 0
    gload_lds16(kgl,                      &sK[0][w * 8][0]);
    gload_lds16(kgl + (size_t)32 * D_,    &sK[0][32 + w * 8][0]);
    gload_lds16(vgl,                      &sV[0][w * 8][0]);
    gload_lds16(vgl + 32 * 1024,          &sV[0][32 + w * 8][0]);
    asm volatile("s_waitcnt vmcnt(0)" ::: "memory");
    __builtin_amdgcn_s_barrier();

    int buf = 0;
    for (int kt = 0; kt < 16; kt++) {
        if (kt < 15) {
            int m1 = (kt + 1) * 64;
            gload_lds16(kgl + (size_t)m1 * D_,        &sK[buf ^ 1][w * 8][0]);
            gload_lds16(kgl + (size_t)(m1 + 32) * D_, &sK[buf ^ 1][32 + w * 8][0]);
            gload_lds16(vgl + m1,                     &sV[buf ^ 1][w * 8][0]);
            gload_lds16(vgl + 32 * 1024 + m1,         &sV[buf ^ 1][32 + w * 8][0]);
        }

        // S^T = mfma(K, Q): lane holds S2[q=c15][key = j*16 + quad*4 + r]
        floatx4 sfr[2][4];
        __builtin_amdgcn_s_setprio(1);
#pragma unroll
        for (int j = 0; j < 4; j++) {
            const bf16* kp = &sK[buf][j * 16 + c15][0];
            bf16x8 k0 = *(const bf16x8*)(kp + s0);
            bf16x8 k1 = *(const bf16x8*)(kp + s1);
#pragma unroll
            for (int h = 0; h < 2; h++) {
                floatx4 z = (floatx4){0.f, 0.f, 0.f, 0.f};
                z = MFMA16(k0, aq[h][0], z, 0, 0, 0);
                z = MFMA16(k1, aq[h][1], z, 0, 0, 0);
                sfr[h][j] = z;
            }
        }
        __builtin_amdgcn_s_setprio(0);

        // hoist V fragments into registers (latency hides under softmax VALU)
        bf16x8 vf0[4], vf1[4];
#pragma unroll
        for (int j = 0; j < 4; j++) {
            const bf16* vp = &sV[buf][j * 16 + c15][0];
            vf0[j] = *(const bf16x8*)(vp + s0);
            vf1[j] = *(const bf16x8*)(vp + s1);
        }

        // per half: softmax (exp2 domain, defer-max, tree reduce) then PV.
        // sP rows (c15) are reused by both halves; per-wave in-order DS pipe
        // orders h1's stores after h0's reads.
#pragma unroll
        for (int h = 0; h < 2; h++) {
            float q0 = fmaxf(fmaxf(sfr[h][0][0], sfr[h][0][1]), fmaxf(sfr[h][0][2], sfr[h][0][3]));
            float q1 = fmaxf(fmaxf(sfr[h][1][0], sfr[h][1][1]), fmaxf(sfr[h][1][2], sfr[h][1][3]));
            float q2 = fmaxf(fmaxf(sfr[h][2][0], sfr[h][2][1]), fmaxf(sfr[h][2][2], sfr[h][2][3]));
            float q3 = fmaxf(fmaxf(sfr[h][3][0], sfr[h][3][1]), fmaxf(sfr[h][3][2], sfr[h][3][3]));
            float mx = fmaxf(fmaxf(q0, q1), fmaxf(q2, q3));
            if (__any(mx > m_sw[h] + 11.0f)) {   // rare: real rescale
                float mr = fmaxf(mx, __shfl_xor(mx, 16, 64));
                mr = fmaxf(mr, __shfl_xor(mr, 32, 64));
                float mnew = fmaxf(m_sw[h], mr);
                float alpha = exp2_fast(m_sw[h] - mnew);
                l_sw[h] *= alpha;
                m_sw[h] = mnew;
#pragma unroll
                for (int r = 0; r < 4; r++) {
                    float a = __shfl(alpha, quad * 4 + r, 64);
#pragma unroll
                    for (int j = 0; j < 4; j++) o_acc[h][j][r] *= a;
                }
            }
            float m = m_sw[h];
            float pe[4][4];
            bf16x4 pk[4];
#pragma unroll
            for (int j = 0; j < 4; j++)
#pragma unroll
                for (int r = 0; r < 4; r++) {
                    float p = exp2_fast(sfr[h][j][r] - m);
                    pe[j][r] = p;
                    pk[j][r] = (bf16)p;
                }
            float f0 = (pe[0][0] + pe[0][1]) + (pe[0][2] + pe[0][3]);
            float f1 = (pe[1][0] + pe[1][1]) + (pe[1][2] + pe[1][3]);
            float f2 = (pe[2][0] + pe[2][1]) + (pe[2][2] + pe[2][3]);
            float f3 = (pe[3][0] + pe[3][1]) + (pe[3][2] + pe[3][3]);
            float sum = (f0 + f1) + (f2 + f3);
            sum += __shfl_xor(sum, 16, 64);
            sum += __shfl_xor(sum, 32, 64);
            l_sw[h] += sum;

            // store P row q=c15 (b64, XOR-swizzled cols)
            bf16* pw = &sP[w][c15][0];
#pragma unroll
            for (int j = 0; j < 4; j++)
                *(bf16x4*)(pw + (((j * 16 + quad * 4)) ^ spx)) = pk[j];

            // wave-local ordering only (sP is wave-private)
            asm volatile("s_waitcnt lgkmcnt(0)" ::: "memory");
            __builtin_amdgcn_sched_barrier(0);

            bf16x8 ap0 = *(const bf16x8*)(pw + ((quad * 8) ^ spx));
            bf16x8 ap1 = *(const bf16x8*)(pw + ((32 + quad * 8) ^ spx));
            __builtin_amdgcn_s_setprio(1);
#pragma unroll
            for (int j = 0; j < 4; j++) {
                o_acc[h][j] = MFMA16(ap0, vf0[j], o_acc[h][j], 0, 0, 0);
                o_acc[h][j] = MFMA16(ap1, vf1[j], o_acc[h][j], 0, 0, 0);
            }
            __builtin_amdgcn_s_setprio(0);
        }

        if (kt < 15) {
            asm volatile("s_waitcnt vmcnt(0)" ::: "memory");
            __builtin_amdgcn_s_barrier();
            buf ^= 1;
        }
    }

    // epilogue: O/l, atomically accumulate branches into zeroed fp32 out
#pragma unroll
    for (int h = 0; h < 2; h++) {
        float inv = 1.0f / l_sw[h];
#pragma unroll
        for (int r = 0; r < 4; r++) {
            float iv = __shfl(inv, quad * 4 + r, 64);
            int row = n0 + w * 32 + h * 16 + quad * 4 + r;
            float* op = out + ((size_t)batch * N_ + row) * D_ + colOff;
#pragma unroll
            for (int j = 0; j < 4; j++) {
                float v = o_acc[h][j][r] * iv;
                int col = j * 16 + c15;
                unsafeAtomicAdd(op + col, v);
            }
        }
    }
}

// ---------------------------------------------------------------------------
extern "C" void kernel_launch(void* const* d_in, const int* in_sizes, int n_in,
                              void* d_out, int out_size, void* d_ws, size_t ws_size,
                              hipStream_t stream) {
    const float* x  = (const float*)d_in[0];
    const float* wq = (const float*)d_in[1];
    const float* bq = (const float*)d_in[2];
    const float* wk = (const float*)d_in[3];
    const float* bk = (const float*)d_in[4];
    const float* wv = (const float*)d_in[5];
    const float* bv = (const float*)d_in[6];
    float* out = (float*)d_out;

    char* ws = (char*)d_ws;
    bf16*  xbf = (bf16*)ws;                                   // 12,582,912 B
    bf16*  wbf = (bf16*)(ws + 12582912);                      // 10,616,832 B
    float* sc  = (float*)(ws + 12582912 + 10616832);          //     65,536 B
    bf16*  qkv = (bf16*)(ws + 12582912 + 10616832 + 65536);   // up to 9 matrices

    const size_t matB = (size_t)M_ * D_ * 2;                  // 12,582,912 B
    const size_t need_all = 12582912 + 10616832 + 65536 + 9 * matB;  // ~136.5 MB

    hipMemsetAsync(d_out, 0, out_size, stream);
    hipLaunchKernelGGL(prep_x, dim3(M_), dim3(192), 0, stream, x, xbf, sc);
    hipLaunchKernelGGL(prep_w, dim3((9 * WSZ_ / 4) / 256), dim3(256), 0, stream, wq, wk, wv, wbf);

    if (ws_size >= need_all) {
        hipLaunchKernelGGL(gemm_qkv9, dim3(864), dim3(512), 0, stream,
                           xbf, wbf, bq, bk, bv, sc, qkv);
        hipLaunchKernelGGL(attn, dim3(N_ / 128, B_ * H_, 3), dim3(256), 0, stream,
                           qkv, out);
    } else {
        for (int br = 0; br < 3; br++) {
            hipLaunchKernelGGL(gemm_qkv, dim3(D_ / BN, M_ / BM, 3), dim3(256), 0, stream,
                               xbf, wbf, bq, bk, bv, sc, br * 3, qkv);
            hipLaunchKernelGGL(attn, dim3(N_ / 128, B_ * H_, 1), dim3(256), 0, stream,
                               qkv, out);
        }
    }
}

// Round 10
// 359.213 us; speedup vs baseline: 1.1766x; 1.1766x over previous
//
#include <hip/hip_runtime.h>
#include <hip/hip_bf16.h>
#include <cstdint>
#include <cstddef>

// Problem shape (fixed by reference): B=8, N=1024, D=768, H=12, dh=64, 3 branches
#define B_   8
#define N_   1024
#define D_   768
#define H_   12
#define DH_  64
#define M_   (B_ * N_)          // 8192 rows
#define WSZ_ (D_ * D_)          // 589824 per weight matrix

typedef __bf16 bf16;
typedef bf16  bf16x8  __attribute__((ext_vector_type(8)));
typedef bf16  bf16x4  __attribute__((ext_vector_type(4)));
typedef float floatx4 __attribute__((ext_vector_type(4)));

#define MFMA16 __builtin_amdgcn_mfma_f32_16x16x32_bf16

// raw v_exp_f32: D = 2^S0
__device__ __forceinline__ float exp2_fast(float x) {
    float r;
    asm("v_exp_f32 %0, %1" : "=v"(r) : "v"(x));
    return r;
}

// ---------------------------------------------------------------------------
// async global->LDS, 16B per lane (wave-uniform LDS base + lane*16)
__device__ __forceinline__ void gload_lds16(const void* g, void* l) {
    __builtin_amdgcn_global_load_lds(
        (const __attribute__((address_space(1))) unsigned int*)g,
        (__attribute__((address_space(3))) unsigned int*)l, 16, 0, 0);
}

// ---------------------------------------------------------------------------
// Kernel 1: per-row norm -> branch scales; x -> bf16.
// One wave per row (4 rows/block): 3x float4 per lane, shfl-only reduce.
__global__ __launch_bounds__(256) void prep_x(const float* __restrict__ x,
                                              bf16* __restrict__ xbf,
                                              float* __restrict__ sc /* [2][M_] */) {
    int wv = threadIdx.x >> 6, lane = threadIdx.x & 63;
    int row = blockIdx.x * 4 + wv;
    const float* xr = x + (size_t)row * D_;
    bf16* xo = xbf + (size_t)row * D_;
    float ss = 0.f;
#pragma unroll
    for (int k = 0; k < 3; k++) {
        float4 v = *(const float4*)(xr + lane * 4 + k * 256);
        bf16x4 o = { (bf16)v.x, (bf16)v.y, (bf16)v.z, (bf16)v.w };
        *(bf16x4*)(xo + lane * 4 + k * 256) = o;
        ss += v.x * v.x + v.y * v.y + v.z * v.z + v.w * v.w;
    }
    for (int off = 32; off; off >>= 1) ss += __shfl_xor(ss, off, 64);
    if (lane == 0) {
        float t  = sqrtf(ss);                       // true ||x||
        const float scst = 0.31622776601683794f;    // sqrt(0.1)
        float un = fmaxf(t, 1e-5f);
        float s1 = tanhf(scst * un) / (scst * un);
        float nh = fmaxf(t * s1, 1e-5f);
        float maxnorm = (1.0f - 4e-3f) / scst;
        float sh = (nh > maxnorm) ? s1 * (maxnorm / nh) : s1;
        float arg = fminf(scst * un, 1.0f - 1e-5f);
        float artanh = 0.5f * logf((1.0f + arg) / (1.0f - arg));
        float ssc = artanh / (un * scst);
        sc[row]      = sh;
        sc[M_ + row] = ssc;
    }
}

// ---------------------------------------------------------------------------
// Kernel 2: weights fp32 -> bf16, layout wbf[branch][t][o][k] == stacked [6912][768]
__global__ __launch_bounds__(256) void prep_w(const float* __restrict__ wq,
                                              const float* __restrict__ wk,
                                              const float* __restrict__ wv,
                                              bf16* __restrict__ wbf) {
    size_t i = ((size_t)blockIdx.x * 256 + threadIdx.x) * 4;  // 9*WSZ_ total
    int z = (int)(i / WSZ_);
    int r = (int)(i % WSZ_);
    int branch = z / 3, t = z % 3;
    const float* src = (t == 0 ? wq : t == 1 ? wk : wv) + (size_t)branch * WSZ_ + r;
    float4 f = *(const float4*)src;
    bf16x4 o = { (bf16)f.x, (bf16)f.y, (bf16)f.z, (bf16)f.w };
    *(bf16x4*)(wbf + i) = o;
}

// ---------------------------------------------------------------------------
// Kernel 3 (merged path, verified r6/r7): 256x256-tile 8-phase pipelined GEMM
// over stacked N = 9*768. For t==2 (V) the output is written TRANSPOSED per
// (b,h): vt[b][h][dd][n] (bf16x4 packs along n).
#define NT9 12   // K tiles: 768/64

#define STG(buf, mat, half, t) do {                                          \
    const bf16* _src = (mat) ? wbf : xbf;                                    \
    int _rb = ((mat) ? bn0 : bm0) + (half) * 128 + w * 16 + (lane >> 2);     \
    const bf16* _g = _src + (size_t)_rb * D_ + (t) * 64 + (lane & 3) * 8;    \
    bf16* _l = &L[buf][mat][half][0][w * 16][0];                             \
    gload_lds16(_g, _l);                                                     \
    gload_lds16(_g + 32, _l + 4096);                                         \
} while (0)

#define LOADA(buf, mh) do {                                                  \
    _Pragma("unroll") for (int fi = 0; fi < 4; fi++)                         \
    _Pragma("unroll") for (int kk = 0; kk < 2; kk++)                         \
        afr[fi][kk] = *(const bf16x8*)(&L[buf][0][wm][kk][(mh)*64 + fi*16 + c15][quad*8]); \
} while (0)

#define LOADB(buf, nh) do {                                                  \
    _Pragma("unroll") for (int fj = 0; fj < 2; fj++)                         \
    _Pragma("unroll") for (int kk = 0; kk < 2; kk++)                         \
        bfr[nh][fj][kk] = *(const bf16x8*)(&L[buf][1][wn>>1][kk][(wn&1)*64 + (nh)*32 + fj*16 + c15][quad*8]); \
} while (0)

#define MFMACL(mh, nh) do {                                                  \
    __builtin_amdgcn_s_setprio(1);                                           \
    _Pragma("unroll") for (int fi = 0; fi < 4; fi++)                         \
    _Pragma("unroll") for (int fj = 0; fj < 2; fj++)                         \
    _Pragma("unroll") for (int kk = 0; kk < 2; kk++)                         \
        acc[(mh)*4 + fi][(nh)*2 + fj] =                                      \
            MFMA16(afr[fi][kk], bfr[nh][fj][kk], acc[(mh)*4 + fi][(nh)*2 + fj], 0, 0, 0); \
    __builtin_amdgcn_s_setprio(0);                                           \
} while (0)

#define BAR() __builtin_amdgcn_s_barrier()
#define VMW4() asm volatile("s_waitcnt vmcnt(4)" ::: "memory")

__global__ __launch_bounds__(512, 2) void gemm_qkv9(
        const bf16* __restrict__ xbf, const bf16* __restrict__ wbf,
        const float* __restrict__ bq, const float* __restrict__ bk,
        const float* __restrict__ bv, const float* __restrict__ sc,
        bf16* __restrict__ qkv) {
    int bid = blockIdx.x;
    int v = (bid & 7) * 108 + (bid >> 3);   // 864 = 8*108, bijective
    int bx = v >> 5;                        // N-panel (0..26)
    int by = v & 31;                        // M-panel (0..31)
    int bn0 = bx * 256;
    int bm0 = by * 256;

    __shared__ bf16 L[2][2][2][2][128][32]; // 128 KiB

    int tid = threadIdx.x;
    int w = tid >> 6, lane = tid & 63;
    int wm = w >> 2, wn = w & 3;
    int quad = lane >> 4, c15 = lane & 15;

    bf16x8 afr[4][2];
    bf16x8 bfr[2][2][2];
    floatx4 acc[8][4];
#pragma unroll
    for (int i = 0; i < 8; i++)
#pragma unroll
        for (int j = 0; j < 4; j++) acc[i][j] = (floatx4){0.f, 0.f, 0.f, 0.f};

    STG(0, 0, 0, 0); STG(0, 0, 1, 0); STG(0, 1, 0, 0); STG(0, 1, 1, 0);
    STG(1, 1, 0, 1); STG(1, 1, 1, 1);
    VMW4();
    BAR();

    for (int it = 0; it < 6; it++) {
        int t1 = 2 * it + 1;
        bool st2 = (it < 5);
        LOADA(0, 0); LOADB(0, 0);
        STG(1, 0, 0, t1);
        BAR(); MFMACL(0, 0); BAR();
        LOADB(0, 1);
        STG(1, 0, 1, t1);
        BAR(); MFMACL(0, 1); BAR();
        LOADA(0, 1);
        if (st2) STG(0, 1, 0, t1 + 1);
        BAR(); MFMACL(1, 1); BAR();
        if (st2) STG(0, 1, 1, t1 + 1);
        VMW4();
        BAR(); MFMACL(1, 0); BAR();
        LOADA(1, 0); LOADB(1, 0);
        if (st2) STG(0, 0, 0, t1 + 1);
        BAR(); MFMACL(0, 0); BAR();
        LOADB(1, 1);
        if (st2) STG(0, 0, 1, t1 + 1);
        BAR(); MFMACL(0, 1); BAR();
        LOADA(1, 1);
        if (st2) STG(1, 1, 0, t1 + 2);
        BAR(); MFMACL(1, 1); BAR();
        if (st2) STG(1, 1, 1, t1 + 2);
        VMW4();
        BAR(); MFMACL(1, 0); BAR();
    }

    // epilogue: y = s[row]*y + bias[col]
    int gz = bn0 / 768;
    int branch = gz / 3, t = gz % 3;
    int colz0 = (bn0 % 768) + wn * 64;
    const float* bias = (t == 0 ? bq : t == 1 ? bk : bv) + branch * D_;
    const float* scb = (branch == 0) ? nullptr : sc + (size_t)(branch - 1) * M_;
    float bj[4];
#pragma unroll
    for (int fj = 0; fj < 4; fj++) bj[fj] = bias[colz0 + fj * 16 + c15];
    bf16* outz = qkv + (size_t)gz * M_ * D_;
#pragma unroll
    for (int fi = 0; fi < 8; fi++) {
        int rowbase = bm0 + wm * 128 + fi * 16 + quad * 4;
        float4 sv = scb ? *(const float4*)(scb + rowbase)
                        : (float4){1.f, 1.f, 1.f, 1.f};
        float svr[4] = { sv.x, sv.y, sv.z, sv.w };
        if (t == 2) {
            // V: write transposed vt[b][h][dd][n], bf16x4 along n
            int b = rowbase >> 10, nn = rowbase & 1023;
#pragma unroll
            for (int fj = 0; fj < 4; fj++) {
                int col = colz0 + fj * 16 + c15;
                int h = col >> 6, dd = col & 63;
                bf16x4 pkv;
#pragma unroll
                for (int r = 0; r < 4; r++)
                    pkv[r] = (bf16)(svr[r] * acc[fi][fj][r] + bj[fj]);
                *(bf16x4*)(outz + (((size_t)(b * H_ + h) * 64 + dd) << 10) + nn) = pkv;
            }
        } else {
#pragma unroll
            for (int r = 0; r < 4; r++) {
                bf16* orow = outz + (size_t)(rowbase + r) * D_;
#pragma unroll
                for (int fj = 0; fj < 4; fj++)
                    orow[colz0 + fj * 16 + c15] = (bf16)(svr[r] * acc[fi][fj][r] + bj[fj]);
            }
        }
    }
}

// ---------------------------------------------------------------------------
// Kernel 3b (fallback path): 128x128 m97-style GEMM; t==2 writes V^T layout.
#define BM 128
#define BN 128
#define BK 32
__global__ __launch_bounds__(256) void gemm_qkv(
        const bf16* __restrict__ xbf, const bf16* __restrict__ wbf_all,
        const float* __restrict__ bq, const float* __restrict__ bk,
        const float* __restrict__ bv, const float* __restrict__ sc,
        int zoff, bf16* __restrict__ qkv) {
    int gz = zoff + blockIdx.z;
    int branch = gz / 3, t = gz % 3;
    const bf16*  wsrc = wbf_all + (size_t)gz * WSZ_;
    const float* bias = (t == 0 ? bq : t == 1 ? bk : bv) + branch * D_;
    bf16* out = qkv + (size_t)blockIdx.z * M_ * D_;
    int bm0 = blockIdx.y * BM;
    int bn0 = blockIdx.x * BN;

    __shared__ bf16 lA[BM * BK];
    __shared__ bf16 lB[BN * BK];

    int tid = threadIdx.x;
    int w = tid >> 6, lane = tid & 63;
    int wr = w >> 1, wc = w & 1;
    int quad = lane >> 4, c15 = lane & 15;
    int lrow = lane >> 2;
    int lcol = (lane & 3) * 8;

    floatx4 acc[4][4];
    for (int i = 0; i < 4; i++)
        for (int j = 0; j < 4; j++)
            acc[i][j] = (floatx4){0.f, 0.f, 0.f, 0.f};

    for (int k0 = 0; k0 < D_; k0 += BK) {
        const bf16* ga = xbf  + ((size_t)(bm0 + w * 32 + lrow) * D_ + k0 + lcol);
        const bf16* gb = wsrc + ((size_t)(bn0 + w * 32 + lrow) * D_ + k0 + lcol);
        gload_lds16(ga,           (char*)lA + w * 2048);
        gload_lds16(ga + 16 * D_, (char*)lA + w * 2048 + 1024);
        gload_lds16(gb,           (char*)lB + w * 2048);
        gload_lds16(gb + 16 * D_, (char*)lB + w * 2048 + 1024);
        __syncthreads();

        int arow = wr * 64 + c15;
        int brow = wc * 64 + c15;
        int kq = quad * 8;
        bf16x8 af[4], bfm[4];
        for (int i = 0; i < 4; i++) af[i]  = *(const bf16x8*)(lA + (arow + i * 16) * BK + kq);
        for (int j = 0; j < 4; j++) bfm[j] = *(const bf16x8*)(lB + (brow + j * 16) * BK + kq);
        for (int i = 0; i < 4; i++)
            for (int j = 0; j < 4; j++)
                acc[i][j] = MFMA16(af[i], bfm[j], acc[i][j], 0, 0, 0);
        __syncthreads();
    }

    const float* scb = (branch == 0) ? nullptr : sc + (size_t)(branch - 1) * M_;
    float bj[4];
    for (int j = 0; j < 4; j++) bj[j] = bias[bn0 + wc * 64 + j * 16 + c15];
    for (int i = 0; i < 4; i++) {
        int gRow0 = bm0 + wr * 64 + i * 16 + quad * 4;
        float s[4];
        for (int r = 0; r < 4; r++) s[r] = scb ? scb[gRow0 + r] : 1.0f;
        if (t == 2) {
            int b = gRow0 >> 10, nn = gRow0 & 1023;
            for (int j = 0; j < 4; j++) {
                int col = bn0 + wc * 64 + j * 16 + c15;
                int h = col >> 6, dd = col & 63;
                bf16x4 pkv;
                for (int r = 0; r < 4; r++)
                    pkv[r] = (bf16)(s[r] * acc[i][j][r] + bj[j]);
                *(bf16x4*)(out + (((size_t)(b * H_ + h) * 64 + dd) << 10) + nn) = pkv;
            }
        } else {
            for (int r = 0; r < 4; r++) {
                bf16* orow = out + (size_t)(gRow0 + r) * D_;
                for (int j = 0; j < 4; j++) {
                    int gCol = bn0 + wc * 64 + j * 16 + c15;
                    orow[gCol] = (bf16)(s[r] * acc[i][j][r] + bj[j]);
                }
            }
        }
    }
}

// ---------------------------------------------------------------------------
// Kernel 4: flash attention (verified round-6 version, 149.8 us). blockIdx.z
// = branch. Double-buffered async K/V^T staging (source-swizzle pair),
// swapped QK^T, in-register exp2 softmax with defer-max (both halves'
// chains kept independent — do NOT serialize them, see r9 post-mortem),
// atomic accumulate into zeroed out.
#define LDKP 72
__global__ __launch_bounds__(256) void attn(const bf16* __restrict__ qkv,
                                            float* __restrict__ out) {
    int qt = blockIdx.x;              // 0..7 (128 q rows each)
    int bh = blockIdx.y;              // 0..95
    int br = blockIdx.z;
    int batch = bh / H_, head = bh % H_;
    int n0 = qt * 128;
    int tid = threadIdx.x, w = tid >> 6, lane = tid & 63;
    int quad = lane >> 4, c15 = lane & 15;

    const bf16* base = qkv + (size_t)br * 3 * M_ * D_;
    size_t baseRow = (size_t)batch * N_;
    int colOff = head * DH_;
    const bf16* qb  = base;
    const bf16* kb  = base + (size_t)M_ * D_;
    const bf16* vtb = base + (size_t)2 * M_ * D_
                    + ((size_t)(batch * H_ + head) * 64) * 1024;

    __shared__ bf16 sK[2][64][64];       // 16 KB
    __shared__ bf16 sV[2][64][64];       // 16 KB
    __shared__ bf16 sP[4][32 * LDKP];    // 18 KB, wave-private
    bf16* sPw = sP[w];

    int lr  = lane >> 3;
    int swz = ((lane & 7) ^ lr) * 8;     // global column (elements)
    const bf16* kgl = kb  + (baseRow + w * 8 + lr) * D_ + colOff + swz;
    const bf16* vgl = vtb + ((size_t)(w * 8 + lr)) * 1024 + swz;

    int s0 = (quad ^ (c15 & 7)) * 8;
    int s1 = s0 ^ 32;

    // Q fragments for both 16-row halves, pre-scaled by log2(e)
    bf16x8 aq[2][2];
#pragma unroll
    for (int h = 0; h < 2; h++) {
        const bf16* qp = qb + ((baseRow + n0 + w * 32 + h * 16 + c15) * D_ + colOff + quad * 8);
        aq[h][0] = *(const bf16x8*)qp;
        aq[h][1] = *(const bf16x8*)(qp + 32);
#pragma unroll
        for (int f = 0; f < 2; f++)
#pragma unroll
            for (int i = 0; i < 8; i++)
                aq[h][f][i] = (bf16)((float)aq[h][f][i] * 1.4426950408889634f);
    }

    float m_sw[2] = { 0.f, 0.f };
    float l_sw[2] = { 0.f, 0.f };
    floatx4 o_acc[2][4];
#pragma unroll
    for (int h = 0; h < 2; h++)
#pragma unroll
        for (int j = 0; j < 4; j++) o_acc[h][j] = (floatx4){0.f, 0.f, 0.f, 0.f};

    // prologue: stage tile 0 into buf 0
    gload_lds16(kgl,                      &sK[0][w * 8][0]);
    gload_lds16(kgl + (size_t)32 * D_,    &sK[0][32 + w * 8][0]);
    gload_lds16(vgl,                      &sV[0][w * 8][0]);
    gload_lds16(vgl + 32 * 1024,          &sV[0][32 + w * 8][0]);
    asm volatile("s_waitcnt vmcnt(0)" ::: "memory");
    __builtin_amdgcn_s_barrier();

    int buf = 0;
    for (int kt = 0; kt < 16; kt++) {
        if (kt < 15) {
            int m1 = (kt + 1) * 64;
            gload_lds16(kgl + (size_t)m1 * D_,        &sK[buf ^ 1][w * 8][0]);
            gload_lds16(kgl + (size_t)(m1 + 32) * D_, &sK[buf ^ 1][32 + w * 8][0]);
            gload_lds16(vgl + m1,                     &sV[buf ^ 1][w * 8][0]);
            gload_lds16(vgl + 32 * 1024 + m1,         &sV[buf ^ 1][32 + w * 8][0]);
        }

        floatx4 sfr[2][4];
        __builtin_amdgcn_s_setprio(1);
#pragma unroll
        for (int j = 0; j < 4; j++) {
            const bf16* kp = &sK[buf][j * 16 + c15][0];
            bf16x8 k0 = *(const bf16x8*)(kp + s0);
            bf16x8 k1 = *(const bf16x8*)(kp + s1);
#pragma unroll
            for (int h = 0; h < 2; h++) {
                floatx4 z = (floatx4){0.f, 0.f, 0.f, 0.f};
                z = MFMA16(k0, aq[h][0], z, 0, 0, 0);
                z = MFMA16(k1, aq[h][1], z, 0, 0, 0);
                sfr[h][j] = z;
            }
        }
        __builtin_amdgcn_s_setprio(0);

#pragma unroll
        for (int h = 0; h < 2; h++) {
            float q0 = fmaxf(fmaxf(sfr[h][0][0], sfr[h][0][1]), fmaxf(sfr[h][0][2], sfr[h][0][3]));
            float q1 = fmaxf(fmaxf(sfr[h][1][0], sfr[h][1][1]), fmaxf(sfr[h][1][2], sfr[h][1][3]));
            float q2 = fmaxf(fmaxf(sfr[h][2][0], sfr[h][2][1]), fmaxf(sfr[h][2][2], sfr[h][2][3]));
            float q3 = fmaxf(fmaxf(sfr[h][3][0], sfr[h][3][1]), fmaxf(sfr[h][3][2], sfr[h][3][3]));
            float mx = fmaxf(fmaxf(q0, q1), fmaxf(q2, q3));
            if (__any(mx > m_sw[h] + 11.0f)) {
                float mr = fmaxf(mx, __shfl_xor(mx, 16, 64));
                mr = fmaxf(mr, __shfl_xor(mr, 32, 64));
                float mnew = fmaxf(m_sw[h], mr);
                float alpha = exp2_fast(m_sw[h] - mnew);
                l_sw[h] *= alpha;
                m_sw[h] = mnew;
#pragma unroll
                for (int r = 0; r < 4; r++) {
                    float a = __shfl(alpha, quad * 4 + r, 64);
#pragma unroll
                    for (int j = 0; j < 4; j++) o_acc[h][j][r] *= a;
                }
            }
            float m = m_sw[h];
            float pe[4][4];
            bf16x4 pk[4];
#pragma unroll
            for (int j = 0; j < 4; j++)
#pragma unroll
                for (int r = 0; r < 4; r++) {
                    float p = exp2_fast(sfr[h][j][r] - m);
                    pe[j][r] = p;
                    pk[j][r] = (bf16)p;
                }
            float f0 = (pe[0][0] + pe[0][1]) + (pe[0][2] + pe[0][3]);
            float f1 = (pe[1][0] + pe[1][1]) + (pe[1][2] + pe[1][3]);
            float f2 = (pe[2][0] + pe[2][1]) + (pe[2][2] + pe[2][3]);
            float f3 = (pe[3][0] + pe[3][1]) + (pe[3][2] + pe[3][3]);
            float sum = (f0 + f1) + (f2 + f3);
            sum += __shfl_xor(sum, 16, 64);
            sum += __shfl_xor(sum, 32, 64);
            l_sw[h] += sum;
            bf16* pw = sPw + (h * 16 + c15) * LDKP;
#pragma unroll
            for (int j = 0; j < 4; j++)
                *(bf16x4*)(pw + j * 16 + quad * 4) = pk[j];
        }

        asm volatile("s_waitcnt lgkmcnt(0)" ::: "memory");
        __builtin_amdgcn_sched_barrier(0);

        bf16x8 ap[2][2];
#pragma unroll
        for (int h = 0; h < 2; h++) {
            const bf16* pp = sPw + (h * 16 + c15) * LDKP + quad * 8;
            ap[h][0] = *(const bf16x8*)pp;
            ap[h][1] = *(const bf16x8*)(pp + 32);
        }
        __builtin_amdgcn_s_setprio(1);
#pragma unroll
        for (int j = 0; j < 4; j++) {
            const bf16* vp = &sV[buf][j * 16 + c15][0];
            bf16x8 v0 = *(const bf16x8*)(vp + s0);
            bf16x8 v1 = *(const bf16x8*)(vp + s1);
#pragma unroll
            for (int h = 0; h < 2; h++) {
                o_acc[h][j] = MFMA16(ap[h][0], v0, o_acc[h][j], 0, 0, 0);
                o_acc[h][j] = MFMA16(ap[h][1], v1, o_acc[h][j], 0, 0, 0);
            }
        }
        __builtin_amdgcn_s_setprio(0);

        if (kt < 15) {
            asm volatile("s_waitcnt vmcnt(0)" ::: "memory");
            __builtin_amdgcn_s_barrier();
            buf ^= 1;
        }
    }

    // epilogue: O/l, atomically accumulate branches into zeroed fp32 out
#pragma unroll
    for (int h = 0; h < 2; h++) {
        float inv = 1.0f / l_sw[h];
#pragma unroll
        for (int r = 0; r < 4; r++) {
            float iv = __shfl(inv, quad * 4 + r, 64);
            int row = n0 + w * 32 + h * 16 + quad * 4 + r;
            float* op = out + ((size_t)batch * N_ + row) * D_ + colOff;
#pragma unroll
            for (int j = 0; j < 4; j++) {
                float v = o_acc[h][j][r] * iv;
                int col = j * 16 + c15;
                unsafeAtomicAdd(op + col, v);
            }
        }
    }
}

// ---------------------------------------------------------------------------
extern "C" void kernel_launch(void* const* d_in, const int* in_sizes, int n_in,
                              void* d_out, int out_size, void* d_ws, size_t ws_size,
                              hipStream_t stream) {
    const float* x  = (const float*)d_in[0];
    const float* wq = (const float*)d_in[1];
    const float* bq = (const float*)d_in[2];
    const float* wk = (const float*)d_in[3];
    const float* bk = (const float*)d_in[4];
    const float* wv = (const float*)d_in[5];
    const float* bv = (const float*)d_in[6];
    float* out = (float*)d_out;

    char* ws = (char*)d_ws;
    bf16*  xbf = (bf16*)ws;                                   // 12,582,912 B
    bf16*  wbf = (bf16*)(ws + 12582912);                      // 10,616,832 B
    float* sc  = (float*)(ws + 12582912 + 10616832);          //     65,536 B
    bf16*  qkv = (bf16*)(ws + 12582912 + 10616832 + 65536);   // up to 9 matrices

    const size_t matB = (size_t)M_ * D_ * 2;                  // 12,582,912 B
    const size_t need_all = 12582912 + 10616832 + 65536 + 9 * matB;  // ~136.5 MB

    hipMemsetAsync(d_out, 0, out_size, stream);
    hipLaunchKernelGGL(prep_x, dim3(M_ / 4), dim3(256), 0, stream, x, xbf, sc);
    hipLaunchKernelGGL(prep_w, dim3((9 * WSZ_ / 4) / 256), dim3(256), 0, stream, wq, wk, wv, wbf);

    if (ws_size >= need_all) {
        hipLaunchKernelGGL(gemm_qkv9, dim3(864), dim3(512), 0, stream,
                           xbf, wbf, bq, bk, bv, sc, qkv);
        hipLaunchKernelGGL(attn, dim3(N_ / 128, B_ * H_, 3), dim3(256), 0, stream,
                           qkv, out);
    } else {
        for (int br = 0; br < 3; br++) {
            hipLaunchKernelGGL(gemm_qkv, dim3(D_ / BN, M_ / BM, 3), dim3(256), 0, stream,
                               xbf, wbf, bq, bk, bv, sc, br * 3, qkv);
            hipLaunchKernelGGL(attn, dim3(N_ / 128, B_ * H_, 1), dim3(256), 0, stream,
                               qkv, out);
        }
    }
}